// Round 9
// baseline (125.556 us; speedup 1.0000x reference)
//
#include <hip/hip_runtime.h>
#include <hip/hip_bf16.h>

typedef unsigned short ushort_t;
typedef __attribute__((ext_vector_type(4))) float f32x4;
typedef __attribute__((ext_vector_type(8))) short bf16x8;
typedef __attribute__((ext_vector_type(8))) unsigned short u16x8;

#define M_DIM 2048
#define N_DIM 4096
#define K_DIM 4096

#define MFMA16(a, b, c) __builtin_amdgcn_mfma_f32_16x16x32_bf16((a), (b), (c), 0, 0, 0)

// ---------- helpers ----------
__device__ __forceinline__ unsigned short f2bf(float f) {
  unsigned int u = __float_as_uint(f);
  u += 0x7FFFu + ((u >> 16) & 1u);   // round-to-nearest-even
  return (unsigned short)(u >> 16);
}
__device__ __forceinline__ float bf2f(unsigned short u) {
  return __uint_as_float(((unsigned int)u) << 16);
}

__device__ __forceinline__ void async16(void* l, const void* g) {
  __builtin_amdgcn_global_load_lds(
      (const __attribute__((address_space(1))) void*)g,
      (__attribute__((address_space(3))) void*)l,
      16, 0, 0);
}

// ---------- kernel 1: fused [x fp32->bf16] + [W build, c1 staged in LDS] ----------
// (unchanged from round 5: ~26us)
__global__ void k_prep(const float* __restrict__ x, ushort_t* __restrict__ o,
                       const float* __restrict__ c0, const float* __restrict__ c1,
                       const float* __restrict__ c2, ushort_t* __restrict__ wt) {
  __shared__ float sc1[16 * 260];
  const int bid = blockIdx.x;
  const int tid = threadIdx.x;
  if (bid < 2048) {
    const int n4 = (M_DIM * K_DIM) / 4;
    for (int i = bid * 256 + tid; i < n4; i += 2048 * 256) {
      float4 v = ((const float4*)x)[i];
      ushort4 r;
      r.x = f2bf(v.x); r.y = f2bf(v.y); r.z = f2bf(v.z); r.w = f2bf(v.w);
      ((ushort4*)o)[i] = r;
    }
  } else {
    const int out = bid - 2048;
    const int o3 = out & 15;
    const int o2 = (out >> 4) & 15;
    const int o1 = out >> 8;
    {
      const int q  = tid >> 4;
      const int i2 = tid & 15;
      const float* src = c1 + q * 4096 + i2 * 256 + o2 * 16;
      float* dst = &sc1[i2 * 260 + q * 16];
      #pragma unroll
      for (int rr = 0; rr < 4; ++rr)
        *(float4*)(dst + rr * 4) = *(const float4*)(src + rr * 4);
    }
    __syncthreads();

    const int i2 = tid & 15;
    const int i1 = tid >> 4;
    float4 a4[4];
    {
      const float* c0p = c0 + (i1 * 16 + o1) * 16;
      #pragma unroll
      for (int rr = 0; rr < 4; ++rr) a4[rr] = *(const float4*)(c0p + rr * 4);
    }
    float t01r[16];
    #pragma unroll
    for (int r = 0; r < 16; ++r) t01r[r] = 0.f;
    #pragma unroll
    for (int q = 0; q < 16; ++q) {
      const float a = a4[q >> 2][q & 3];
      const float* sp = &sc1[i2 * 260 + q * 16];
      #pragma unroll
      for (int rr = 0; rr < 4; ++rr) {
        float4 v = *(const float4*)(sp + rr * 4);
        t01r[rr * 4 + 0] += a * v.x;
        t01r[rr * 4 + 1] += a * v.y;
        t01r[rr * 4 + 2] += a * v.z;
        t01r[rr * 4 + 3] += a * v.w;
      }
    }
    u16x8 lo, hi;
    #pragma unroll
    for (int i3 = 0; i3 < 16; ++i3) {
      const float* c2p = c2 + i3 * 16 + o3;
      float s = 0.f;
      #pragma unroll
      for (int rr = 0; rr < 16; ++rr) s += t01r[rr] * c2p[rr * 256];
      ushort_t v = f2bf(s);
      if (i3 < 8) lo[i3] = v; else hi[i3 - 8] = v;
    }
    u16x8* dst = (u16x8*)(wt + ((size_t)out << 12) + (i1 << 8) + (i2 << 4));
    dst[0] = lo;
    dst[1] = hi;
  }
}

// ---------- kernel 2a: split-K 256^2 GEMM, 4-phase/tile m201-style schedule ----
// 8 waves (2M x 4N), wave-tile 128x64, BK=64, 2 LDS slots (128KB), prefetch-1.
// kz=0 -> f32 partial into d_out (no bias); kz=1 -> bf16 partial into ws.
__global__ __launch_bounds__(512, 1) void k_gemm_sk(
    const ushort_t* __restrict__ A,
    const ushort_t* __restrict__ Bt,
    float* __restrict__ C0,
    ushort_t* __restrict__ P1b)
{
  __shared__ ushort_t lA[2][256 * 64];   // 2 x 32KB
  __shared__ ushort_t lB[2][256 * 64];   // 2 x 32KB

  const int tid  = threadIdx.x;
  const int lane = tid & 63;
  const int wid  = tid >> 6;     // 0..7
  const int wm   = wid >> 2;     // 0..1  (M half, 128 rows)
  const int wn   = wid & 3;      // 0..3  (N quarter, 64 cols)
  const int fr   = lane & 15;
  const int fg   = lane >> 4;    // 0..3

  // bm = bid&7 -> XCD owns one 2MB A-panel (L2-fit); bn/kz from the rest
  const int bid = blockIdx.x;
  const int bm  = bid & 7;            // 0..7
  const int rst = bid >> 3;           // 0..31
  const int bn  = rst & 15;           // 0..15
  const int kz  = rst >> 4;           // 0..1

  // ---- staging (linear LDS dest + inverse-swizzled global source) ----
  const int srow = tid >> 3;                               // 0..63
  const int scol = ((tid & 7) ^ (srow & 7)) << 3;          // swizzled source col
  const ushort_t* aSt = A  + (size_t)(bm * 256 + srow) * K_DIM + kz * 2048 + scol;
  const ushort_t* bSt = Bt + (size_t)(bn * 256 + srow) * K_DIM + kz * 2048 + scol;
  const int dE = tid * 8;

  // round r4: 64 rows each (4 rounds = 256 rows), 1 gload per thread per round
#define SA(kt, s, r4) async16(&lA[s][(r4) * 4096 + dE], \
                              aSt + (size_t)(kt) * 64 + (size_t)(r4) * 64 * K_DIM)
#define SB(kt, s, r4) async16(&lB[s][(r4) * 4096 + dE], \
                              bSt + (size_t)(kt) * 64 + (size_t)(r4) * 64 * K_DIM)

  // ---- fragment read addressing (swizzle on read; verified 0 conflicts) ----
  const int aRow = (wm * 128 + fr) * 64;     // + mf*16*64
  const int bRow = (wn * 64 + fr) * 64;      // + n*16*64
  const int cs0 = ( fg      ^ (fr & 7)) << 3;
  const int cs1 = ((fg + 4) ^ (fr & 7)) << 3;

  f32x4 acc[8][4];
  #pragma unroll
  for (int m = 0; m < 8; ++m)
    #pragma unroll
    for (int n = 0; n < 4; ++n)
      acc[m][n] = (f32x4){0.f, 0.f, 0.f, 0.f};

  // prologue: stage tile 0 into slot 0, drain, barrier
  SA(0, 0, 0); SA(0, 0, 1); SA(0, 0, 2); SA(0, 0, 3);
  SB(0, 0, 0); SB(0, 0, 1); SB(0, 0, 2); SB(0, 0, 3);
  asm volatile("s_waitcnt vmcnt(0)" ::: "memory");
  __builtin_amdgcn_s_barrier();

  for (int t = 0; t < 32; ++t) {
    const int s = t & 1;
    const bool pre = (t + 1 < 32);
    const ushort_t* pA = &lA[s][0];
    const ushort_t* pB = &lB[s][0];

    bf16x8 b0[4], b1[4], af[4];

    // ---- P1: reads B(kk0) + A(mh0,kk0); stage A(t+1); MFMA mh0 kk0 ----
    #pragma unroll
    for (int n = 0; n < 4; ++n) b0[n] = *(const bf16x8*)(pB + bRow + n * 1024 + cs0);
    #pragma unroll
    for (int m = 0; m < 4; ++m) af[m] = *(const bf16x8*)(pA + aRow + m * 1024 + cs0);
    if (pre) { SA(t + 1, s ^ 1, 0); SA(t + 1, s ^ 1, 1); SA(t + 1, s ^ 1, 2); SA(t + 1, s ^ 1, 3); }
    __builtin_amdgcn_s_barrier();
    __builtin_amdgcn_s_setprio(1);
    #pragma unroll
    for (int m = 0; m < 4; ++m)
      #pragma unroll
      for (int n = 0; n < 4; ++n)
        acc[m][n] = MFMA16(af[m], b0[n], acc[m][n]);
    __builtin_amdgcn_s_setprio(0);
    __builtin_amdgcn_s_barrier();

    // ---- P2: reads A(mh1,kk0); stage B(t+1); MFMA mh1 kk0 ----
    #pragma unroll
    for (int m = 0; m < 4; ++m) af[m] = *(const bf16x8*)(pA + aRow + (4 + m) * 1024 + cs0);
    if (pre) { SB(t + 1, s ^ 1, 0); SB(t + 1, s ^ 1, 1); SB(t + 1, s ^ 1, 2); SB(t + 1, s ^ 1, 3); }
    __builtin_amdgcn_s_barrier();
    __builtin_amdgcn_s_setprio(1);
    #pragma unroll
    for (int m = 0; m < 4; ++m)
      #pragma unroll
      for (int n = 0; n < 4; ++n)
        acc[4 + m][n] = MFMA16(af[m], b0[n], acc[4 + m][n]);
    __builtin_amdgcn_s_setprio(0);
    __builtin_amdgcn_s_barrier();

    // ---- P3: reads B(kk1) + A(mh0,kk1); MFMA mh0 kk1 ----
    #pragma unroll
    for (int n = 0; n < 4; ++n) b1[n] = *(const bf16x8*)(pB + bRow + n * 1024 + cs1);
    #pragma unroll
    for (int m = 0; m < 4; ++m) af[m] = *(const bf16x8*)(pA + aRow + m * 1024 + cs1);
    __builtin_amdgcn_s_barrier();
    __builtin_amdgcn_s_setprio(1);
    #pragma unroll
    for (int m = 0; m < 4; ++m)
      #pragma unroll
      for (int n = 0; n < 4; ++n)
        acc[m][n] = MFMA16(af[m], b1[n], acc[m][n]);
    __builtin_amdgcn_s_setprio(0);
    __builtin_amdgcn_s_barrier();

    // ---- P4: reads A(mh1,kk1); vmcnt(0) (stages ~2 phases old); MFMA mh1 kk1 ----
    #pragma unroll
    for (int m = 0; m < 4; ++m) af[m] = *(const bf16x8*)(pA + aRow + (4 + m) * 1024 + cs1);
    asm volatile("s_waitcnt vmcnt(0)" ::: "memory");   // tile t+1 resident
    __builtin_amdgcn_s_barrier();
    __builtin_amdgcn_s_setprio(1);
    #pragma unroll
    for (int m = 0; m < 4; ++m)
      #pragma unroll
      for (int n = 0; n < 4; ++n)
        acc[4 + m][n] = MFMA16(af[m], b1[n], acc[4 + m][n]);
    __builtin_amdgcn_s_setprio(0);
    __builtin_amdgcn_s_barrier();   // all slot-s reads done before t+1 stages slot s
  }
#undef SA
#undef SB

  // epilogue: C/D layout col = lane&15, row = (lane>>4)*4 + reg
  const size_t row0 = (size_t)bm * 256 + wm * 128;
  const int col0 = bn * 256 + wn * 64;
  if (kz == 0) {
    #pragma unroll
    for (int n = 0; n < 4; ++n) {
      const int col = col0 + n * 16 + fr;
      #pragma unroll
      for (int m = 0; m < 8; ++m) {
        const size_t r0 = row0 + m * 16 + fg * 4;
        #pragma unroll
        for (int r = 0; r < 4; ++r)
          C0[(r0 + r) * N_DIM + col] = acc[m][n][r];
      }
    }
  } else {
    #pragma unroll
    for (int n = 0; n < 4; ++n) {
      const int col = col0 + n * 16 + fr;
      #pragma unroll
      for (int m = 0; m < 8; ++m) {
        const size_t r0 = row0 + m * 16 + fg * 4;
        #pragma unroll
        for (int r = 0; r < 4; ++r)
          P1b[(r0 + r) * N_DIM + col] = f2bf(acc[m][n][r]);
      }
    }
  }
}

// ---------- kernel 2b: fallback (round-5 kernel, ~80us, bias fused) ----------
__global__ __launch_bounds__(512, 2) void k_gemm_fb(
    const ushort_t* __restrict__ A,
    const ushort_t* __restrict__ Bt,
    const float* __restrict__ bias,
    float* __restrict__ C)
{
  __shared__ ushort_t lA[3][128 * 128];  // 3 x 32KB (256x64 tiles)
  __shared__ ushort_t lB[3][64 * 128];   // 3 x 16KB

  const int tid  = threadIdx.x;
  const int lane = tid & 63;
  const int wid  = tid >> 6;
  const int wm   = wid >> 1;
  const int wn   = wid & 1;
  const int fr   = lane & 15;
  const int fg   = lane >> 4;

  const int bid = blockIdx.x;
  const int bm  = bid & 7;
  const int bn  = bid >> 3;

  const int srow = tid >> 3;
  const int scol = ((tid & 7) ^ (srow & 7)) << 3;
  const ushort_t* aSt = A  + (size_t)(bm * 256 + srow) * K_DIM + scol;
  const ushort_t* bSt = Bt + (size_t)(bn * 128 + srow) * K_DIM + scol;
  const int dE = tid * 8;

#define STAGE_A(kt, s, r_) async16(&lA[s][(r_) * 4096 + dE], \
                                   aSt + (size_t)(kt) * 64 + (size_t)(r_) * 64 * K_DIM)
#define STAGE_B(kt, s, r_) async16(&lB[s][(r_) * 4096 + dE], \
                                   bSt + (size_t)(kt) * 64 + (size_t)(r_) * 64 * K_DIM)

  const int arowb = wm * 64 + fr;
  const int browb = wn * 64 + fr;
  const int c0 = ( fg      ^ (fr & 7)) << 3;
  const int c1 = ((fg + 4) ^ (fr & 7)) << 3;

  f32x4 acc[4][4];
  #pragma unroll
  for (int m = 0; m < 4; ++m)
    #pragma unroll
    for (int n = 0; n < 4; ++n)
      acc[m][n] = (f32x4){0.f, 0.f, 0.f, 0.f};

  #pragma unroll
  for (int r_ = 0; r_ < 4; ++r_) STAGE_A(0, 0, r_);
  #pragma unroll
  for (int r_ = 0; r_ < 2; ++r_) STAGE_B(0, 0, r_);
  #pragma unroll
  for (int r_ = 0; r_ < 4; ++r_) STAGE_A(1, 1, r_);
  #pragma unroll
  for (int r_ = 0; r_ < 2; ++r_) STAGE_B(1, 1, r_);

  asm volatile("s_waitcnt vmcnt(6)" ::: "memory");
  __builtin_amdgcn_s_barrier();

  int sc = 0, ss = 2;
  for (int t = 0; t < 64; ++t) {
    const bool pre = (t + 2 < 64);
    const ushort_t* pA = &lA[sc][0];
    const ushort_t* pB = &lB[sc][0];
    {
      bf16x8 af[4], bf[4];
      #pragma unroll
      for (int m = 0; m < 4; ++m) af[m] = *(const bf16x8*)(pA + (arowb + m * 16) * 64 + c0);
      #pragma unroll
      for (int n = 0; n < 4; ++n) bf[n] = *(const bf16x8*)(pB + (browb + n * 16) * 64 + c0);
      if (pre) { STAGE_A(t + 2, ss, 0); STAGE_A(t + 2, ss, 1); STAGE_A(t + 2, ss, 2); }
      __builtin_amdgcn_s_barrier();
      __builtin_amdgcn_s_setprio(1);
      #pragma unroll
      for (int m = 0; m < 4; ++m)
        #pragma unroll
        for (int n = 0; n < 4; ++n)
          acc[m][n] = MFMA16(af[m], bf[n], acc[m][n]);
      __builtin_amdgcn_s_setprio(0);
      __builtin_amdgcn_s_barrier();
    }
    {
      bf16x8 af[4], bf[4];
      #pragma unroll
      for (int m = 0; m < 4; ++m) af[m] = *(const bf16x8*)(pA + (arowb + m * 16) * 64 + c1);
      #pragma unroll
      for (int n = 0; n < 4; ++n) bf[n] = *(const bf16x8*)(pB + (browb + n * 16) * 64 + c1);
      if (pre) { STAGE_A(t + 2, ss, 3); STAGE_B(t + 2, ss, 0); STAGE_B(t + 2, ss, 1); }
      __builtin_amdgcn_s_barrier();
      __builtin_amdgcn_s_setprio(1);
      #pragma unroll
      for (int m = 0; m < 4; ++m)
        #pragma unroll
        for (int n = 0; n < 4; ++n)
          acc[m][n] = MFMA16(af[m], bf[n], acc[m][n]);
      __builtin_amdgcn_s_setprio(0);
      if (t + 2 < 64)      asm volatile("s_waitcnt vmcnt(6)" ::: "memory");
      else if (t + 1 < 64) asm volatile("s_waitcnt vmcnt(0)" ::: "memory");
      __builtin_amdgcn_s_barrier();
    }
    sc = (sc == 2) ? 0 : sc + 1;
    ss = (ss == 2) ? 0 : ss + 1;
  }
#undef STAGE_A
#undef STAGE_B

  const size_t row0 = (size_t)bm * 256 + wm * 64;
  const int col0 = bn * 128 + wn * 64;
  #pragma unroll
  for (int n = 0; n < 4; ++n) {
    const int col = col0 + n * 16 + fr;
    const float bv = bias[col];
    #pragma unroll
    for (int m = 0; m < 4; ++m) {
      const size_t r0 = row0 + m * 16 + fg * 4;
      #pragma unroll
      for (int r = 0; r < 4; ++r)
        C[(r0 + r) * N_DIM + col] = acc[m][n][r] + bv;
    }
  }
}

// ---------- kernel 3: out = out(kz0 f32) + bf16(kz1 partial) + bias ----------
__global__ void k_reduce(float* __restrict__ out, const ushort_t* __restrict__ p1,
                         const float* __restrict__ bias) {
  const int idx = blockIdx.x * 256 + threadIdx.x;   // 1M threads, 8 elems each
  const int base = idx * 8;
  const int col = base & (N_DIM - 1);
  float4 o0 = *(float4*)(out + base);
  float4 o1 = *(float4*)(out + base + 4);
  u16x8 p = *(const u16x8*)(p1 + base);
  float4 b0 = *(const float4*)(bias + col);
  float4 b1 = *(const float4*)(bias + col + 4);
  o0.x += bf2f(p[0]) + b0.x;  o0.y += bf2f(p[1]) + b0.y;
  o0.z += bf2f(p[2]) + b0.z;  o0.w += bf2f(p[3]) + b0.w;
  o1.x += bf2f(p[4]) + b1.x;  o1.y += bf2f(p[5]) + b1.y;
  o1.z += bf2f(p[6]) + b1.z;  o1.w += bf2f(p[7]) + b1.w;
  *(float4*)(out + base)     = o0;
  *(float4*)(out + base + 4) = o1;
}

// ---------- launch ----------
extern "C" void kernel_launch(void* const* d_in, const int* in_sizes, int n_in,
                              void* d_out, int out_size, void* d_ws, size_t ws_size,
                              hipStream_t stream) {
  const float* x    = (const float*)d_in[0];
  const float* c0   = (const float*)d_in[1];
  const float* c1   = (const float*)d_in[2];
  const float* c2   = (const float*)d_in[3];
  const float* bias = (const float*)d_in[4];
  float* out = (float*)d_out;

  const size_t MB = 1024 * 1024;
  if (ws_size < 48 * MB) return;

  char* ws = (char*)d_ws;
  ushort_t* Abf = (ushort_t*)ws;
  ushort_t* Wt  = (ushort_t*)(ws + 16 * MB);

  k_prep<<<6144, 256, 0, stream>>>(x, Abf, c0, c1, c2, Wt);

  if (ws_size >= 64 * MB) {
    ushort_t* P1b = (ushort_t*)(ws + 48 * MB);
    k_gemm_sk<<<256, 512, 0, stream>>>(Abf, Wt, out, P1b);
    k_reduce <<<4096, 256, 0, stream>>>(out, P1b, bias);
  } else {
    k_gemm_fb<<<256, 512, 0, stream>>>(Abf, Wt, bias, out);
  }
}